// Round 3
// baseline (625.010 us; speedup 1.0000x reference)
//
#include <hip/hip_runtime.h>
#include <hip/hip_bf16.h>

// ---------- 1. GEMM: Hp = H (N x 128) * W (128 x 128), fp32 ----------
// Block: 256 threads -> 16 rows x 64 cols (grid.y selects col half).
__global__ __launch_bounds__(256) void gemm_kernel(
    const float* __restrict__ H, const float* __restrict__ Wg,
    float* __restrict__ Hp, int N)
{
    __shared__ float Wl[128 * 64];   // W[k][c] for this col half  (32 KB)
    __shared__ float Hl[16 * 128];   // 16 rows of H               (8 KB)
    const int tid = threadIdx.x;
    const int ch  = blockIdx.y;            // 0/1 col half
    const int row0 = blockIdx.x * 16;

    // load W half (8192 floats), coalesced float4
    for (int i = tid * 4; i < 128 * 64; i += 256 * 4) {
        int k = i >> 6, c = i & 63;
        *(float4*)&Wl[i] = *(const float4*)&Wg[k * 128 + ch * 64 + c];
    }
    // load 16 H rows (2048 floats)
    for (int i = tid * 4; i < 16 * 128; i += 256 * 4) {
        int rr = row0 + (i >> 7);
        if (rr < N)
            *(float4*)&Hl[i] = *(const float4*)&H[(size_t)rr * 128 + (i & 127)];
    }
    __syncthreads();

    const int rb = tid >> 4;        // 0..15 row in block
    const int cq = tid & 15;        // col quad
    const int row = row0 + rb;
    if (row >= N) return;

    const float4* Wl4 = (const float4*)Wl;
    float4 acc = {0.f, 0.f, 0.f, 0.f};
    #pragma unroll 4
    for (int k = 0; k < 128; ++k) {
        float hv = Hl[rb * 128 + k];
        float4 w = Wl4[k * 16 + cq];
        acc.x = fmaf(hv, w.x, acc.x);
        acc.y = fmaf(hv, w.y, acc.y);
        acc.z = fmaf(hv, w.z, acc.z);
        acc.w = fmaf(hv, w.w, acc.w);
    }
    *(float4*)&Hp[(size_t)row * 128 + ch * 64 + cq * 4] = acc;
}

// ---------- 2a. histogram of edge rows ----------
__global__ __launch_bounds__(256) void hist_kernel(
    const int* __restrict__ row, int* __restrict__ counts, int E)
{
    int e = blockIdx.x * 256 + threadIdx.x;
    if (e < E) atomicAdd(&counts[row[e]], 1);
}

// ---------- 2b. exclusive scan (single block, 1024 threads) ----------
__global__ __launch_bounds__(1024) void scan_kernel(
    const int* __restrict__ counts, int* __restrict__ rowptr,
    int* __restrict__ rowwork, int N, int E)
{
    __shared__ int sums[1024];
    const int tid = threadIdx.x;
    const int chunk = (N + 1023) >> 10;
    const int lo = tid * chunk;
    const int hi = min(lo + chunk, N);
    int s = 0;
    for (int i = lo; i < hi; ++i) s += counts[i];
    sums[tid] = s;
    __syncthreads();
    for (int d = 1; d < 1024; d <<= 1) {
        int t = (tid >= d) ? sums[tid - d] : 0;
        __syncthreads();
        sums[tid] += t;
        __syncthreads();
    }
    int off = sums[tid] - s;   // exclusive prefix
    for (int i = lo; i < hi; ++i) {
        rowptr[i] = off;
        rowwork[i] = off;
        off += counts[i];
    }
    if (tid == 0) rowptr[N] = E;
}

// ---------- 2c. scatter edges into row-sorted order ----------
__global__ __launch_bounds__(256) void scatter_kernel(
    const int* __restrict__ row, const int* __restrict__ col,
    int* __restrict__ rowwork, int* __restrict__ colsort, int E)
{
    int e = blockIdx.x * 256 + threadIdx.x;
    if (e < E) {
        int r = row[e];
        int pos = atomicAdd(&rowwork[r], 1);
        colsort[pos] = col[e];
    }
}

// ---------- 3. fused score + softmax + aggregate ----------
// One wave per row. lane = g*16 + d : g = edge group (4), d = dim slot
// (8 consecutive dims each). Single pass: numerator & denominator together.
__global__ __launch_bounds__(256) void aggregate_kernel(
    const float* __restrict__ Hp, const int* __restrict__ rowptr,
    const int* __restrict__ cols, const float* __restrict__ bias,
    float* __restrict__ out, int N)
{
    const int lane = threadIdx.x & 63;
    const int wv   = threadIdx.x >> 6;
    const int r = blockIdx.x * 4 + wv;
    if (r >= N) return;
    const int d = lane & 15;
    const int g = lane >> 4;

    const float4* HpR = (const float4*)&Hp[(size_t)r * 128 + d * 8];
    const float4 hr0 = HpR[0], hr1 = HpR[1];

    float acc[8] = {0.f,0.f,0.f,0.f,0.f,0.f,0.f,0.f};
    float den = 0.f;
    const int e0 = rowptr[r], e1 = rowptr[r + 1];

    for (int e = e0 + g; e < e1; e += 4) {
        int c = cols[e];
        const float4* HpC = (const float4*)&Hp[(size_t)c * 128 + d * 8];
        float4 hc0 = HpC[0], hc1 = HpC[1];
        float dot = hr0.x*hc0.x + hr0.y*hc0.y + hr0.z*hc0.z + hr0.w*hc0.w
                  + hr1.x*hc1.x + hr1.y*hc1.y + hr1.z*hc1.z + hr1.w*hc1.w;
        dot += __shfl_xor(dot, 1);
        dot += __shfl_xor(dot, 2);
        dot += __shfl_xor(dot, 4);
        dot += __shfl_xor(dot, 8);
        float s  = dot > 0.f ? dot : 0.2f * dot;   // leaky_relu(0.2)
        float ex = __expf(s);
        den += ex;
        acc[0] = fmaf(ex, hc0.x, acc[0]);
        acc[1] = fmaf(ex, hc0.y, acc[1]);
        acc[2] = fmaf(ex, hc0.z, acc[2]);
        acc[3] = fmaf(ex, hc0.w, acc[3]);
        acc[4] = fmaf(ex, hc1.x, acc[4]);
        acc[5] = fmaf(ex, hc1.y, acc[5]);
        acc[6] = fmaf(ex, hc1.z, acc[6]);
        acc[7] = fmaf(ex, hc1.w, acc[7]);
    }

    #pragma unroll
    for (int k = 0; k < 8; ++k) {
        acc[k] += __shfl_xor(acc[k], 16);
        acc[k] += __shfl_xor(acc[k], 32);
    }
    den += __shfl_xor(den, 16);
    den += __shfl_xor(den, 32);

    if (g == 0) {
        float inv = 1.f / (den + 1e-10f);
        const float4* bp = (const float4*)&bias[d * 8];
        float4 b0 = bp[0], b1 = bp[1];
        float4 o0, o1;
        o0.x = fmaf(acc[0], inv, b0.x);
        o0.y = fmaf(acc[1], inv, b0.y);
        o0.z = fmaf(acc[2], inv, b0.z);
        o0.w = fmaf(acc[3], inv, b0.w);
        o1.x = fmaf(acc[4], inv, b1.x);
        o1.y = fmaf(acc[5], inv, b1.y);
        o1.z = fmaf(acc[6], inv, b1.z);
        o1.w = fmaf(acc[7], inv, b1.w);
        float4* op = (float4*)&out[(size_t)r * 128 + d * 8];
        op[0] = o0;
        op[1] = o1;
    }
}

extern "C" void kernel_launch(void* const* d_in, const int* in_sizes, int n_in,
                              void* d_out, int out_size, void* d_ws, size_t ws_size,
                              hipStream_t stream)
{
    const float* H    = (const float*)d_in[0];
    const float* W    = (const float*)d_in[1];
    const float* bias = (const float*)d_in[2];
    const int*   row  = (const int*)d_in[3];
    const int*   col  = (const int*)d_in[4];
    const int N = in_sizes[0] / 128;
    const int E = in_sizes[3];

    // workspace layout (~58.8 MB total)
    char* ws = (char*)d_ws;
    size_t off = 0;
    float* Hp      = (float*)(ws + off); off += (size_t)N * 128 * 4;
    int*   counts  = (int*)(ws + off);   off += (size_t)(N + 1) * 4;
    int*   rowptr  = (int*)(ws + off);   off += (size_t)(N + 1) * 4;
    int*   rowwork = (int*)(ws + off);   off += (size_t)(N + 1) * 4;
    int*   colsort = (int*)(ws + off);

    (void)hipMemsetAsync(counts, 0, (size_t)N * 4, stream);

    gemm_kernel<<<dim3((N + 15) / 16, 2), 256, 0, stream>>>(H, W, Hp, N);
    hist_kernel<<<(E + 255) / 256, 256, 0, stream>>>(row, counts, E);
    scan_kernel<<<1, 1024, 0, stream>>>(counts, rowptr, rowwork, N, E);
    scatter_kernel<<<(E + 255) / 256, 256, 0, stream>>>(row, col, rowwork, colsort, E);
    aggregate_kernel<<<(N + 3) / 4, 256, 0, stream>>>(Hp, rowptr, colsort, bias,
                                                      (float*)d_out, N);
}

// Round 4
// 406.749 us; speedup vs baseline: 1.5366x; 1.5366x over previous
//
#include <hip/hip_runtime.h>
#include <hip/hip_bf16.h>

#define SCAN_T 256
#define SCAN_K 2
#define SCAN_CHUNK (SCAN_T * SCAN_K)   // 512 counts per block

// ---------- 1. GEMM: Hp = H (N x 128) * W (128 x 128), fp32 ----------
__global__ __launch_bounds__(256) void gemm_kernel(
    const float* __restrict__ H, const float* __restrict__ Wg,
    float* __restrict__ Hp, int N)
{
    __shared__ float Wl[128 * 64];   // W[k][c] for this col half  (32 KB)
    __shared__ float Hl[16 * 128];   // 16 rows of H               (8 KB)
    const int tid = threadIdx.x;
    const int ch  = blockIdx.y;            // 0/1 col half
    const int row0 = blockIdx.x * 16;

    for (int i = tid * 4; i < 128 * 64; i += 256 * 4) {
        int k = i >> 6, c = i & 63;
        *(float4*)&Wl[i] = *(const float4*)&Wg[k * 128 + ch * 64 + c];
    }
    for (int i = tid * 4; i < 16 * 128; i += 256 * 4) {
        int rr = row0 + (i >> 7);
        if (rr < N)
            *(float4*)&Hl[i] = *(const float4*)&H[(size_t)rr * 128 + (i & 127)];
    }
    __syncthreads();

    const int rb = tid >> 4;
    const int cq = tid & 15;
    const int row = row0 + rb;
    if (row >= N) return;

    const float4* Wl4 = (const float4*)Wl;
    float4 acc = {0.f, 0.f, 0.f, 0.f};
    #pragma unroll 4
    for (int k = 0; k < 128; ++k) {
        float hv = Hl[rb * 128 + k];
        float4 w = Wl4[k * 16 + cq];
        acc.x = fmaf(hv, w.x, acc.x);
        acc.y = fmaf(hv, w.y, acc.y);
        acc.z = fmaf(hv, w.z, acc.z);
        acc.w = fmaf(hv, w.w, acc.w);
    }
    *(float4*)&Hp[(size_t)row * 128 + ch * 64 + cq * 4] = acc;
}

// ---------- 2a. histogram of edge rows ----------
__global__ __launch_bounds__(256) void hist_kernel(
    const int* __restrict__ row, int* __restrict__ counts, int E)
{
    int e = blockIdx.x * 256 + threadIdx.x;
    if (e < E) atomicAdd(&counts[row[e]], 1);
}

// ---------- 2b. multi-block exclusive scan (3 phases) ----------
__global__ __launch_bounds__(SCAN_T) void scan_part(
    const int* __restrict__ counts, int* __restrict__ blockSums, int N)
{
    __shared__ int red[SCAN_T];
    const int tid = threadIdx.x;
    const int base = blockIdx.x * SCAN_CHUNK + tid * SCAN_K;
    int s = 0;
    #pragma unroll
    for (int i = 0; i < SCAN_K; ++i) {
        int idx = base + i;
        if (idx < N) s += counts[idx];
    }
    red[tid] = s;
    __syncthreads();
    for (int d = SCAN_T / 2; d > 0; d >>= 1) {
        if (tid < d) red[tid] += red[tid + d];
        __syncthreads();
    }
    if (tid == 0) blockSums[blockIdx.x] = red[0];
}

__global__ __launch_bounds__(1024) void scan_top(
    int* __restrict__ blockSums, int nb)
{
    __shared__ int sums[1024];
    const int tid = threadIdx.x;
    int v = (tid < nb) ? blockSums[tid] : 0;
    sums[tid] = v;
    __syncthreads();
    for (int d = 1; d < 1024; d <<= 1) {
        int t = (tid >= d) ? sums[tid - d] : 0;
        __syncthreads();
        sums[tid] += t;
        __syncthreads();
    }
    if (tid < nb) blockSums[tid] = sums[tid] - v;   // exclusive
}

__global__ __launch_bounds__(SCAN_T) void scan_write(
    const int* __restrict__ counts, const int* __restrict__ blockSums,
    int* __restrict__ rowptr, int* __restrict__ rowwork, int N, int E)
{
    __shared__ int tsum[SCAN_T];
    const int tid = threadIdx.x;
    const int base = blockIdx.x * SCAN_CHUNK + tid * SCAN_K;
    int c[SCAN_K];
    int s = 0;
    #pragma unroll
    for (int i = 0; i < SCAN_K; ++i) {
        int idx = base + i;
        c[i] = (idx < N) ? counts[idx] : 0;
        s += c[i];
    }
    tsum[tid] = s;
    __syncthreads();
    for (int d = 1; d < SCAN_T; d <<= 1) {
        int t = (tid >= d) ? tsum[tid - d] : 0;
        __syncthreads();
        tsum[tid] += t;
        __syncthreads();
    }
    int off = blockSums[blockIdx.x] + tsum[tid] - s;   // exclusive prefix
    #pragma unroll
    for (int i = 0; i < SCAN_K; ++i) {
        int idx = base + i;
        if (idx < N) {
            rowptr[idx] = off;
            rowwork[idx] = off;
            off += c[i];
        }
    }
    if (blockIdx.x == 0 && tid == 0) rowptr[N] = E;
}

// ---------- 2c. scatter edges into row-sorted order ----------
__global__ __launch_bounds__(256) void scatter_kernel(
    const int* __restrict__ row, const int* __restrict__ col,
    int* __restrict__ rowwork, int* __restrict__ colsort, int E)
{
    int e = blockIdx.x * 256 + threadIdx.x;
    if (e < E) {
        int r = row[e];
        int pos = atomicAdd(&rowwork[r], 1);
        colsort[pos] = col[e];
    }
}

// ---------- 3. fused score + softmax + aggregate ----------
__global__ __launch_bounds__(256) void aggregate_kernel(
    const float* __restrict__ Hp, const int* __restrict__ rowptr,
    const int* __restrict__ cols, const float* __restrict__ bias,
    float* __restrict__ out, int N)
{
    const int lane = threadIdx.x & 63;
    const int wv   = threadIdx.x >> 6;
    const int r = blockIdx.x * 4 + wv;
    if (r >= N) return;
    const int d = lane & 15;
    const int g = lane >> 4;

    const float4* HpR = (const float4*)&Hp[(size_t)r * 128 + d * 8];
    const float4 hr0 = HpR[0], hr1 = HpR[1];

    float acc[8] = {0.f,0.f,0.f,0.f,0.f,0.f,0.f,0.f};
    float den = 0.f;
    const int e0 = rowptr[r], e1 = rowptr[r + 1];

    for (int e = e0 + g; e < e1; e += 4) {
        int c = cols[e];
        const float4* HpC = (const float4*)&Hp[(size_t)c * 128 + d * 8];
        float4 hc0 = HpC[0], hc1 = HpC[1];
        float dot = hr0.x*hc0.x + hr0.y*hc0.y + hr0.z*hc0.z + hr0.w*hc0.w
                  + hr1.x*hc1.x + hr1.y*hc1.y + hr1.z*hc1.z + hr1.w*hc1.w;
        dot += __shfl_xor(dot, 1);
        dot += __shfl_xor(dot, 2);
        dot += __shfl_xor(dot, 4);
        dot += __shfl_xor(dot, 8);
        float s  = dot > 0.f ? dot : 0.2f * dot;   // leaky_relu(0.2)
        float ex = __expf(s);
        den += ex;
        acc[0] = fmaf(ex, hc0.x, acc[0]);
        acc[1] = fmaf(ex, hc0.y, acc[1]);
        acc[2] = fmaf(ex, hc0.z, acc[2]);
        acc[3] = fmaf(ex, hc0.w, acc[3]);
        acc[4] = fmaf(ex, hc1.x, acc[4]);
        acc[5] = fmaf(ex, hc1.y, acc[5]);
        acc[6] = fmaf(ex, hc1.z, acc[6]);
        acc[7] = fmaf(ex, hc1.w, acc[7]);
    }

    #pragma unroll
    for (int k = 0; k < 8; ++k) {
        acc[k] += __shfl_xor(acc[k], 16);
        acc[k] += __shfl_xor(acc[k], 32);
    }
    den += __shfl_xor(den, 16);
    den += __shfl_xor(den, 32);

    if (g == 0) {
        float inv = 1.f / (den + 1e-10f);
        const float4* bp = (const float4*)&bias[d * 8];
        float4 b0 = bp[0], b1 = bp[1];
        float4 o0, o1;
        o0.x = fmaf(acc[0], inv, b0.x);
        o0.y = fmaf(acc[1], inv, b0.y);
        o0.z = fmaf(acc[2], inv, b0.z);
        o0.w = fmaf(acc[3], inv, b0.w);
        o1.x = fmaf(acc[4], inv, b1.x);
        o1.y = fmaf(acc[5], inv, b1.y);
        o1.z = fmaf(acc[6], inv, b1.z);
        o1.w = fmaf(acc[7], inv, b1.w);
        float4* op = (float4*)&out[(size_t)r * 128 + d * 8];
        op[0] = o0;
        op[1] = o1;
    }
}

extern "C" void kernel_launch(void* const* d_in, const int* in_sizes, int n_in,
                              void* d_out, int out_size, void* d_ws, size_t ws_size,
                              hipStream_t stream)
{
    const float* H    = (const float*)d_in[0];
    const float* W    = (const float*)d_in[1];
    const float* bias = (const float*)d_in[2];
    const int*   row  = (const int*)d_in[3];
    const int*   col  = (const int*)d_in[4];
    const int N = in_sizes[0] / 128;
    const int E = in_sizes[3];

    // workspace layout (~58.8 MB total)
    char* ws = (char*)d_ws;
    size_t off = 0;
    float* Hp        = (float*)(ws + off); off += (size_t)N * 128 * 4;
    int*   counts    = (int*)(ws + off);   off += (size_t)(N + 1) * 4;
    int*   rowptr    = (int*)(ws + off);   off += (size_t)(N + 1) * 4;
    int*   rowwork   = (int*)(ws + off);   off += (size_t)(N + 1) * 4;
    int*   blockSums = (int*)(ws + off);   off += 1024 * 4;
    int*   colsort   = (int*)(ws + off);

    const int nb = (N + SCAN_CHUNK - 1) / SCAN_CHUNK;   // 196 for N=100000

    (void)hipMemsetAsync(counts, 0, (size_t)N * 4, stream);

    gemm_kernel<<<dim3((N + 15) / 16, 2), 256, 0, stream>>>(H, W, Hp, N);
    hist_kernel<<<(E + 255) / 256, 256, 0, stream>>>(row, counts, E);
    scan_part<<<nb, SCAN_T, 0, stream>>>(counts, blockSums, N);
    scan_top<<<1, 1024, 0, stream>>>(blockSums, nb);
    scan_write<<<nb, SCAN_T, 0, stream>>>(counts, blockSums, rowptr, rowwork, N, E);
    scatter_kernel<<<(E + 255) / 256, 256, 0, stream>>>(row, col, rowwork, colsort, E);
    aggregate_kernel<<<(N + 3) / 4, 256, 0, stream>>>(Hp, rowptr, colsort, bias,
                                                      (float*)d_out, N);
}